// Round 18
// baseline (74.476 us; speedup 1.0000x reference)
//
#include <hip/hip_runtime.h>
#include <hip/hip_bf16.h>

typedef _Float16 f16x8 __attribute__((ext_vector_type(8)));
typedef float f32x4 __attribute__((ext_vector_type(4)));

#define BB 8
#define NN 20
#define KK 5
#define DD 230
#define NQ 200
#define QST 256   // padded Qf row stride (dwords)

#define NB_BFC 240   // build Bfc: 61440 f16 fc fragments
#define NB_BP  200   // build Bp: 51200 f16 conv fragments + tblg
#define NB_CP  180   // 46000 float4 S-copy (256 thr)
#define NB_CONV 575  // conv M-tiles (64 rows)
#define NB_FC2 38    // fc M-tiles (64 rows)
#define NB_ATT 800   // 8 b x 4 n-quarters x 25 q-groups

static __device__ __forceinline__ unsigned int pk2(float a, float b) {
    union { __fp16 h[2] __attribute__((aligned(4))); unsigned int u; } v;
    v.h[0] = (__fp16)a; v.h[1] = (__fp16)b; return v.u;
}

// ============ k_pre: fragment-packed Bfc + Bp + tables + S copy ============
__global__ void k_pre(const float* __restrict__ fc_w,
                      const float* __restrict__ w2, const float* __restrict__ b2,
                      const float* __restrict__ wf,
                      _Float16* __restrict__ Bfc, _Float16* __restrict__ Bp,
                      float2* __restrict__ tblg,
                      const float* __restrict__ S, float* __restrict__ Scopy) {
    const int bid = blockIdx.x, tid = threadIdx.x;
    if (bid < NB_BFC) {
        int g = bid * 256 + tid;             // < 61440
        int kg = g & 31;
        int ncl = (g >> 5) & 15;
        int tk = g >> 9;                     // nt*8+ks
        int nt = tk >> 3, ks = tk & 7;
        int n = nt * 16 + ncl, k = ks * 32 + kg;
        float val = (n < DD && k < DD) ? fc_w[n * DD + k] : 0.f;
        Bfc[g] = (_Float16)val;
    } else if (bid < NB_BFC + NB_BP) {
        int g = (bid - NB_BFC) * 256 + tid;  // < 51200
        int kg = g & 31;
        int ncl = (g >> 5) & 15;
        int tk = g >> 9;                     // nt*5+ks
        int nt = tk / 5, ks = tk - nt * 5;
        int n = nt * 16 + ncl, k = ks * 32 + kg;
        int o = n / 5, i = n % 5;
        int c = k / 5, j = k - c * 5;
        int t = j - i + 2;
        float val = (t >= 0 && t < 5) ? w2[(o * 32 + c) * 5 + t] : 0.f;
        Bp[g] = (_Float16)val;
        if (g < 320) {
            int o2 = g / 5, i2 = g % 5;
            tblg[g] = make_float2(b2[o2], wf[o2 * 5 + i2]);
        }
    } else {
        int g = (bid - NB_BFC - NB_BP) * 256 + tid;
        if (g < 46000) ((float4*)Scopy)[g] = ((const float4*)S)[g];
    }
}

// ============ k_main: conv-as-MFMA (0..574) + fc-as-MFMA (575..612) ============
__global__ __launch_bounds__(512, 8)
void k_main(const float* __restrict__ S, const float* __restrict__ Q,
            const float* __restrict__ w1, const float* __restrict__ b1,
            const _Float16* __restrict__ Bp, const _Float16* __restrict__ Bfc,
            const float2* __restrict__ tblg, float* __restrict__ sc,
            const float* __restrict__ fc_b,
            float* __restrict__ Sf, float* __restrict__ Qf) {
    __shared__ __align__(16) _Float16 XU[64 * 264];   // 33792 B
    __shared__ float xfp[8][2][16];                   //  1024 B
    __shared__ float2 Tbs[320];                       //  2560 B
    const int bid = blockIdx.x, tid = threadIdx.x;
    const int lane = tid & 63;
    const int w = __builtin_amdgcn_readfirstlane(tid >> 6);
    const int ncl = lane & 15;
    const int kg8 = (lane >> 4) * 8;
    const int g4 = lane >> 4;

    if (bid >= NB_CONV) {
        // ---- fc GEMM: 64 rows ----
        const int m0 = (bid - NB_CONV) * 64;
        for (int e = tid; e < 64 * 58; e += 512) {
            int row = e / 58, c4 = e - row * 58;
            int grow = m0 + row;
            float4 v = make_float4(0.f, 0.f, 0.f, 0.f);
            if (grow < 2400) {
                const float* inp = (grow < 800) ? S + (size_t)grow * DD
                                                : Q + (size_t)(grow - 800) * DD;
                if (c4 < 57) v = *(const float4*)&inp[c4 * 4];
                else { v.x = inp[228]; v.y = inp[229]; }
            }
            _Float16* xp = &XU[row * 264 + c4 * 4];
            xp[0] = (_Float16)v.x; xp[1] = (_Float16)v.y;
            xp[2] = (_Float16)v.z; xp[3] = (_Float16)v.w;
        }
        for (int e = tid; e < 64 * 16; e += 512) {
            int row = e >> 4, cc = 232 + (e & 15) * 2;
            *(unsigned int*)&XU[row * 264 + cc] = 0u;
        }
        __syncthreads();

        const int msub = w & 3;
        const int ngrp = w >> 2;
        const int abase = (msub * 16 + ncl) * 264;
        const int nt0 = ngrp * 8;
        const int ntn = ngrp ? 7 : 8;
        for (int ti = 0; ti < ntn; ti++) {
            const int nt = nt0 + ti;
            const _Float16* bp = Bfc + ((size_t)nt * 8 * 16) * 32;
            f32x4 a = {0.f, 0.f, 0.f, 0.f};
#pragma unroll
            for (int ks = 0; ks < 8; ks++) {
                f16x8 br = *(const f16x8*)&bp[(ks * 16 + ncl) * 32 + kg8];
                f16x8 af = *(const f16x8*)&XU[abase + ks * 32 + kg8];
                a = __builtin_amdgcn_mfma_f32_16x16x32_f16(af, br, a, 0, 0, 0);
            }
            const int n = nt * 16 + ncl;
            const float bias = fc_b[n < DD ? n : DD - 1];
            if (n < DD) {
#pragma unroll
                for (int r = 0; r < 4; r++) {
                    int grow = m0 + msub * 16 + g4 * 4 + r;
                    if (grow < 800)
                        Sf[(size_t)grow * DD + n] = (a[r] + bias) * 2.8853900817779268f;
                    else if (grow < 2400)
                        Qf[(size_t)(grow - 800) * QST + n] = a[r] + bias;
                }
            }
        }
        return;
    }

    // ---- conv: 64 M-rows; wave w = (mh = w&1, gq = w>>1 -> tiles gq*5..+4) ----
    const int m0 = bid * 64;
    {
        const int m = m0 + lane;
        const int img = m / DD;
        const int d = m - img * DD;
        const float* sp = S + (size_t)img * KK * DD + d;
        float in5[5];
#pragma unroll
        for (int j = 0; j < 5; j++) in5[j] = sp[j * DD];
#pragma unroll
        for (int cc = 0; cc < 4; cc++) {
            int c = w * 4 + cc;
            float wl[5];
#pragma unroll
            for (int t = 0; t < 5; t++) wl[t] = w1[c * 5 + t];
            float bb = b1[c];
#pragma unroll
            for (int i = 0; i < 5; i++) {
                float a = bb;
#pragma unroll
                for (int t = 0; t < 5; t++) {
                    int j = i + t - 2;
                    if (j >= 0 && j < 5) a = fmaf(wl[t], in5[j], a);
                }
                XU[lane * 168 + c * 5 + i] = (_Float16)fmaxf(a, 0.f);
            }
        }
    }
    if (tid < 320) Tbs[tid] = tblg[tid];
    __syncthreads();

    const int mh = w & 1;
    const int gq = w >> 1;
    const int abase0 = ((mh * 2 + 0) * 16 + ncl) * 168;
    const int abase1 = ((mh * 2 + 1) * 16 + ncl) * 168;

    float xf0 = 0.f, xf1 = 0.f;
    for (int t5 = 0; t5 < 5; t5++) {
        const int nt = gq * 5 + t5;
        const _Float16* bp = Bp + ((size_t)nt * 5 * 16) * 32;
        f32x4 a0 = {0.f, 0.f, 0.f, 0.f}, a1 = {0.f, 0.f, 0.f, 0.f};
#pragma unroll
        for (int ks = 0; ks < 5; ks++) {
            f16x8 br = *(const f16x8*)&bp[(ks * 16 + ncl) * 32 + kg8];
            f16x8 af0 = *(const f16x8*)&XU[abase0 + ks * 32 + kg8];
            f16x8 af1 = *(const f16x8*)&XU[abase1 + ks * 32 + kg8];
            a0 = __builtin_amdgcn_mfma_f32_16x16x32_f16(br, af0, a0, 0, 0, 0);
            a1 = __builtin_amdgcn_mfma_f32_16x16x32_f16(br, af1, a1, 0, 0, 0);
        }
#pragma unroll
        for (int r = 0; r < 4; r++) {
            float2 tb = Tbs[nt * 16 + g4 * 4 + r];
            xf0 = fmaf(fmaxf(a0[r] + tb.x, 0.f), tb.y, xf0);
            xf1 = fmaf(fmaxf(a1[r] + tb.x, 0.f), tb.y, xf1);
        }
    }
    xf0 += __shfl_xor(xf0, 16, 64); xf0 += __shfl_xor(xf0, 32, 64);
    xf1 += __shfl_xor(xf1, 16, 64); xf1 += __shfl_xor(xf1, 32, 64);
    if (lane < 16) { xfp[w][0][lane] = xf0; xfp[w][1][lane] = xf1; }
    __syncthreads();
    if (tid < 64) {
        const int strip = tid >> 4, col = tid & 15;
        const int mhh = strip >> 1, idx = strip & 1;
        float s = xfp[mhh][idx][col] + xfp[mhh + 2][idx][col]
                + xfp[mhh + 4][idx][col] + xfp[mhh + 6][idx][col];
        sc[m0 + strip * 16 + col] = s;
    }
}

// ============ k_att: MFMA-sum tanh logits + softmax + einsum + L2 (LDS-staged) ====
__global__ __launch_bounds__(512, 6)
void k_att(const float* __restrict__ Sf, const float* __restrict__ Qf,
           const float* __restrict__ S, const float* __restrict__ Q,
           const float* __restrict__ sc, const float* __restrict__ convf_b,
           float* __restrict__ out) {
    __shared__ __align__(16) _Float16 SfT[32 * 264];   // 16896 B
    __shared__ __align__(16) float Qs[8][256];         //  8192 B
    __shared__ __align__(16) float St[25 * 232];       // 23200 B
    __shared__ __align__(16) float sct[5 * 232];       //  4640 B
    __shared__ float Lw[8][32];                        //  1024 B
    const int bid = blockIdx.x, tid = threadIdx.x;
    const int lane = tid & 63;
    const int w = __builtin_amdgcn_readfirstlane(tid >> 6);   // 0..7
    const int b = bid / 100;
    const int nq = (bid / 25) & 3;
    const int qg = bid % 25;
    const int q = qg * 8 + w;
    const int n0 = nq * 5;
    const int ncl = lane & 15;
    const int g4 = lane >> 4;
    const int kg8 = g4 * 8;
    const float LOG2E = 1.4426950408889634f;
    const float bf0 = convf_b[0];

    // stage 25 Sf rows as f16, zero-padded to [32][264]
    const float* sfb = Sf + (size_t)(b * 100 + n0 * 5) * DD;
    for (int e = tid; e < 32 * 132; e += 512) {
        int row = e / 132, c2 = e - row * 132;
        unsigned int u = 0u;
        if (row < 25 && c2 <= 114) {
            float2 v = *(const float2*)&sfb[row * DD + 2 * c2];
            u = pk2(v.x, v.y);
        }
        *(unsigned int*)&SfT[row * 264 + 2 * c2] = u;
    }
    // stage the 8 Qf rows (zero pad cols >= 230)
    for (int e = tid; e < 8 * 256; e += 512) {
        int row = e >> 8, col = e & 255;
        float v = 0.f;
        if (col < DD) v = Qf[(size_t)(b * NQ + qg * 8 + row) * QST + col];
        Qs[row][col] = v;
    }
    // stage S tile (25 contiguous rows) and sc tile (5 contiguous rows) as f32
    const float* sS = S + (size_t)(b * NN + n0) * KK * DD;
    for (int e = tid; e < 25 * DD; e += 512) {
        int row = e / DD, col = e - row * DD;
        St[row * 232 + col] = sS[e];
    }
    const float* ssc = sc + (size_t)(b * NN + n0) * DD;
    for (int e = tid; e < 5 * DD; e += 512) {
        int row = e / DD, col = e - row * DD;
        sct[row * 232 + col] = ssc[e];
    }
    __syncthreads();

    // ---- part 1: L[idx] = sum_d tanh(Sf*Qf) via MFMA ones-reduction ----
    f16x8 ones;
#pragma unroll
    for (int j = 0; j < 8; j++) ones[j] = (_Float16)1.f;
    f32x4 acc0 = {0.f, 0.f, 0.f, 0.f}, acc1 = {0.f, 0.f, 0.f, 0.f};

    for (int ks = 0; ks < 8; ks++) {
        f32x4 qa = *(const f32x4*)&Qs[w][ks * 32 + kg8];
        f32x4 qb = *(const f32x4*)&Qs[w][ks * 32 + kg8 + 4];
        float qv[8];
#pragma unroll
        for (int j = 0; j < 4; j++) { qv[j] = qa[j]; qv[4 + j] = qb[j]; }
#pragma unroll
        for (int t = 0; t < 2; t++) {
            f16x8 s8 = *(const f16x8*)&SfT[(t * 16 + ncl) * 264 + ks * 32 + kg8];
            f16x8 vf;
#pragma unroll
            for (int j = 0; j < 8; j++) {
                float x = (float)s8[j] * qv[j];
                float e = __builtin_amdgcn_exp2f(x);
                float v = 1.f - 2.f * __builtin_amdgcn_rcpf(e + 1.f);
                vf[j] = (_Float16)v;
            }
            if (t == 0) acc0 = __builtin_amdgcn_mfma_f32_16x16x32_f16(vf, ones, acc0, 0, 0, 0);
            else        acc1 = __builtin_amdgcn_mfma_f32_16x16x32_f16(vf, ones, acc1, 0, 0, 0);
        }
    }
    if (ncl == 0) {
        *(f32x4*)&Lw[w][g4 * 4] = acc0;
        *(f32x4*)&Lw[w][16 + g4 * 4] = acc1;
    }
    // same-wave produce/consume (compiler inserts lgkmcnt)

    // ---- part 2: softmax(K) + einsum + weighted L2 from LDS tiles ----
    float qr[4];
    const float* qp = Q + (size_t)(b * NQ + q) * DD;
#pragma unroll
    for (int i = 0; i < 4; i++) {
        int d = lane + 64 * i;
        qr[i] = (d < DD) ? qp[d] : 0.f;
    }
    for (int nl = 0; nl < 5; nl++) {
        const float* lp = &Lw[w][nl * 5];
        float v0 = lp[0], v1 = lp[1], v2 = lp[2], v3 = lp[3], v4 = lp[4];
        float m = fmaxf(fmaxf(fmaxf(v0, v1), fmaxf(v2, v3)), v4);
        float e0 = __builtin_amdgcn_exp2f((v0 - m) * LOG2E);
        float e1 = __builtin_amdgcn_exp2f((v1 - m) * LOG2E);
        float e2 = __builtin_amdgcn_exp2f((v2 - m) * LOG2E);
        float e3 = __builtin_amdgcn_exp2f((v3 - m) * LOG2E);
        float e4 = __builtin_amdgcn_exp2f((v4 - m) * LOG2E);
        float inv = __builtin_amdgcn_rcpf(e0 + e1 + e2 + e3 + e4);
        float a0 = e0 * inv, a1 = e1 * inv, a2 = e2 * inv, a3 = e3 * inv, a4 = e4 * inv;
        const float* st = &St[nl * 5 * 232];
        const float* swp = &sct[nl * 232];
        float acc2 = 0.f;
#pragma unroll
        for (int i = 0; i < 4; i++) {
            int d = lane + 64 * i;
            if (d < DD) {
                float rep = a0 * st[d] + a1 * st[232 + d] + a2 * st[464 + d]
                          + a3 * st[696 + d] + a4 * st[928 + d];
                float df = rep - qr[i];
                float scw = fmaxf(swp[d] + bf0, 0.f) * 700.f;
                acc2 = fmaf(df * df, scw, acc2);
            }
        }
#pragma unroll
        for (int off = 32; off > 0; off >>= 1) acc2 += __shfl_xor(acc2, off, 64);
        if (lane == 0) out[((size_t)b * NQ + q) * NN + n0 + nl] = -acc2;
    }
}

extern "C" void kernel_launch(void* const* d_in, const int* in_sizes, int n_in,
                              void* d_out, int out_size, void* d_ws, size_t ws_size,
                              hipStream_t stream) {
    const float* S       = (const float*)d_in[0];
    const float* Q       = (const float*)d_in[1];
    const float* fc_w    = (const float*)d_in[2];
    const float* fc_b    = (const float*)d_in[3];
    const float* conv1_w = (const float*)d_in[4];
    const float* conv1_b = (const float*)d_in[5];
    const float* conv2_w = (const float*)d_in[6];
    const float* conv2_b = (const float*)d_in[7];
    const float* convf_w = (const float*)d_in[8];
    const float* convf_b = (const float*)d_in[9];
    float* out = (float*)d_out;

    float* ws = (float*)d_ws;
    float* Sf  = ws;                               // 184000 dwords
    float* Qf  = Sf + 184000;                      // 409600 (1600 x 256)
    float* sc  = Qf + 409600;                      // 36800
    _Float16* Bp  = (_Float16*)(sc + 36800);       // 51200 f16
    _Float16* Bfc = Bp + 51200;                    // 61440 f16
    float2* tblg  = (float2*)(Bfc + 61440);        // 640 dw

    k_pre<<<NB_BFC + NB_BP + NB_CP, 256, 0, stream>>>(
        fc_w, conv2_w, conv2_b, convf_w, Bfc, Bp, tblg,
        S, out + (size_t)BB * NQ * NN);
    k_main<<<NB_CONV + NB_FC2, 512, 0, stream>>>(
        S, Q, conv1_w, conv1_b, Bp, Bfc, tblg, sc, fc_b, Sf, Qf);
    k_att<<<NB_ATT, 512, 0, stream>>>(
        Sf, Qf, S, Q, sc, convf_b, out);
}

// Round 19
// 66.109 us; speedup vs baseline: 1.1266x; 1.1266x over previous
//
#include <hip/hip_runtime.h>
#include <hip/hip_bf16.h>

typedef _Float16 f16x8 __attribute__((ext_vector_type(8)));
typedef float f32x4 __attribute__((ext_vector_type(4)));

#define BB 8
#define NN 20
#define KK 5
#define DD 230
#define NQ 200
#define QST 256   // padded Qf row stride (dwords)

#define NB_BFC 240   // build Bfc: 61440 f16 fc fragments
#define NB_BP  200   // build Bp: 51200 f16 conv fragments + tblg
#define NB_CP  180   // 46000 float4 S-copy (256 thr)
#define NB_CONV 575  // conv M-tiles (64 rows)
#define NB_FC2 38    // fc M-tiles (64 rows)
#define NB_ATT 800   // 8 b x 4 n-quarters x 25 q-groups

static __device__ __forceinline__ unsigned int pk2(float a, float b) {
    union { __fp16 h[2] __attribute__((aligned(4))); unsigned int u; } v;
    v.h[0] = (__fp16)a; v.h[1] = (__fp16)b; return v.u;
}

// ============ k_pre: fragment-packed Bfc + Bp + tables + S copy ============
__global__ void k_pre(const float* __restrict__ fc_w,
                      const float* __restrict__ w2, const float* __restrict__ b2,
                      const float* __restrict__ wf,
                      _Float16* __restrict__ Bfc, _Float16* __restrict__ Bp,
                      float2* __restrict__ tblg,
                      const float* __restrict__ S, float* __restrict__ Scopy) {
    const int bid = blockIdx.x, tid = threadIdx.x;
    if (bid < NB_BFC) {
        int g = bid * 256 + tid;             // < 61440
        int kg = g & 31;
        int ncl = (g >> 5) & 15;
        int tk = g >> 9;                     // nt*8+ks
        int nt = tk >> 3, ks = tk & 7;
        int n = nt * 16 + ncl, k = ks * 32 + kg;
        float val = (n < DD && k < DD) ? fc_w[n * DD + k] : 0.f;
        Bfc[g] = (_Float16)val;
    } else if (bid < NB_BFC + NB_BP) {
        int g = (bid - NB_BFC) * 256 + tid;  // < 51200
        int kg = g & 31;
        int ncl = (g >> 5) & 15;
        int tk = g >> 9;                     // nt*5+ks
        int nt = tk / 5, ks = tk - nt * 5;
        int n = nt * 16 + ncl, k = ks * 32 + kg;
        int o = n / 5, i = n % 5;
        int c = k / 5, j = k - c * 5;
        int t = j - i + 2;
        float val = (t >= 0 && t < 5) ? w2[(o * 32 + c) * 5 + t] : 0.f;
        Bp[g] = (_Float16)val;
        if (g < 320) {
            int o2 = g / 5, i2 = g % 5;
            tblg[g] = make_float2(b2[o2], wf[o2 * 5 + i2]);
        }
    } else {
        int g = (bid - NB_BFC - NB_BP) * 256 + tid;
        if (g < 46000) ((float4*)Scopy)[g] = ((const float4*)S)[g];
    }
}

// ============ k_main: conv-as-MFMA (0..574) + fc-as-MFMA (575..612) ============
__global__ __launch_bounds__(512, 8)
void k_main(const float* __restrict__ S, const float* __restrict__ Q,
            const float* __restrict__ w1, const float* __restrict__ b1,
            const _Float16* __restrict__ Bp, const _Float16* __restrict__ Bfc,
            const float2* __restrict__ tblg, float* __restrict__ sc,
            const float* __restrict__ fc_b,
            float* __restrict__ Sf, float* __restrict__ Qf) {
    __shared__ __align__(16) _Float16 XU[64 * 264];   // 33792 B
    __shared__ float xfp[8][2][16];                   //  1024 B
    __shared__ float2 Tbs[320];                       //  2560 B
    const int bid = blockIdx.x, tid = threadIdx.x;
    const int lane = tid & 63;
    const int w = __builtin_amdgcn_readfirstlane(tid >> 6);
    const int ncl = lane & 15;
    const int kg8 = (lane >> 4) * 8;
    const int g4 = lane >> 4;

    if (bid >= NB_CONV) {
        // ---- fc GEMM: 64 rows ----
        const int m0 = (bid - NB_CONV) * 64;
        for (int e = tid; e < 64 * 58; e += 512) {
            int row = e / 58, c4 = e - row * 58;
            int grow = m0 + row;
            float4 v = make_float4(0.f, 0.f, 0.f, 0.f);
            if (grow < 2400) {
                const float* inp = (grow < 800) ? S + (size_t)grow * DD
                                                : Q + (size_t)(grow - 800) * DD;
                if (c4 < 57) v = *(const float4*)&inp[c4 * 4];
                else { v.x = inp[228]; v.y = inp[229]; }
            }
            _Float16* xp = &XU[row * 264 + c4 * 4];
            xp[0] = (_Float16)v.x; xp[1] = (_Float16)v.y;
            xp[2] = (_Float16)v.z; xp[3] = (_Float16)v.w;
        }
        for (int e = tid; e < 64 * 16; e += 512) {
            int row = e >> 4, cc = 232 + (e & 15) * 2;
            *(unsigned int*)&XU[row * 264 + cc] = 0u;
        }
        __syncthreads();

        const int msub = w & 3;
        const int ngrp = w >> 2;
        const int abase = (msub * 16 + ncl) * 264;
        const int nt0 = ngrp * 8;
        const int ntn = ngrp ? 7 : 8;
        for (int ti = 0; ti < ntn; ti++) {
            const int nt = nt0 + ti;
            const _Float16* bp = Bfc + ((size_t)nt * 8 * 16) * 32;
            f32x4 a = {0.f, 0.f, 0.f, 0.f};
#pragma unroll
            for (int ks = 0; ks < 8; ks++) {
                f16x8 br = *(const f16x8*)&bp[(ks * 16 + ncl) * 32 + kg8];
                f16x8 af = *(const f16x8*)&XU[abase + ks * 32 + kg8];
                a = __builtin_amdgcn_mfma_f32_16x16x32_f16(af, br, a, 0, 0, 0);
            }
            const int n = nt * 16 + ncl;
            const float bias = fc_b[n < DD ? n : DD - 1];
            if (n < DD) {
#pragma unroll
                for (int r = 0; r < 4; r++) {
                    int grow = m0 + msub * 16 + g4 * 4 + r;
                    if (grow < 800)
                        Sf[(size_t)grow * DD + n] = (a[r] + bias) * 2.8853900817779268f;
                    else if (grow < 2400)
                        Qf[(size_t)(grow - 800) * QST + n] = a[r] + bias;
                }
            }
        }
        return;
    }

    // ---- conv: 64 M-rows; wave w = (mh = w&1, gq = w>>1 -> tiles gq*5..+4) ----
    const int m0 = bid * 64;
    {
        const int m = m0 + lane;
        const int img = m / DD;
        const int d = m - img * DD;
        const float* sp = S + (size_t)img * KK * DD + d;
        float in5[5];
#pragma unroll
        for (int j = 0; j < 5; j++) in5[j] = sp[j * DD];
#pragma unroll
        for (int cc = 0; cc < 4; cc++) {
            int c = w * 4 + cc;
            float wl[5];
#pragma unroll
            for (int t = 0; t < 5; t++) wl[t] = w1[c * 5 + t];
            float bb = b1[c];
#pragma unroll
            for (int i = 0; i < 5; i++) {
                float a = bb;
#pragma unroll
                for (int t = 0; t < 5; t++) {
                    int j = i + t - 2;
                    if (j >= 0 && j < 5) a = fmaf(wl[t], in5[j], a);
                }
                XU[lane * 168 + c * 5 + i] = (_Float16)fmaxf(a, 0.f);
            }
        }
    }
    if (tid < 320) Tbs[tid] = tblg[tid];
    __syncthreads();

    const int mh = w & 1;
    const int gq = w >> 1;
    const int abase0 = ((mh * 2 + 0) * 16 + ncl) * 168;
    const int abase1 = ((mh * 2 + 1) * 16 + ncl) * 168;

    float xf0 = 0.f, xf1 = 0.f;
    for (int t5 = 0; t5 < 5; t5++) {
        const int nt = gq * 5 + t5;
        const _Float16* bp = Bp + ((size_t)nt * 5 * 16) * 32;
        f32x4 a0 = {0.f, 0.f, 0.f, 0.f}, a1 = {0.f, 0.f, 0.f, 0.f};
#pragma unroll
        for (int ks = 0; ks < 5; ks++) {
            f16x8 br = *(const f16x8*)&bp[(ks * 16 + ncl) * 32 + kg8];
            f16x8 af0 = *(const f16x8*)&XU[abase0 + ks * 32 + kg8];
            f16x8 af1 = *(const f16x8*)&XU[abase1 + ks * 32 + kg8];
            a0 = __builtin_amdgcn_mfma_f32_16x16x32_f16(br, af0, a0, 0, 0, 0);
            a1 = __builtin_amdgcn_mfma_f32_16x16x32_f16(br, af1, a1, 0, 0, 0);
        }
#pragma unroll
        for (int r = 0; r < 4; r++) {
            float2 tb = Tbs[nt * 16 + g4 * 4 + r];
            xf0 = fmaf(fmaxf(a0[r] + tb.x, 0.f), tb.y, xf0);
            xf1 = fmaf(fmaxf(a1[r] + tb.x, 0.f), tb.y, xf1);
        }
    }
    xf0 += __shfl_xor(xf0, 16, 64); xf0 += __shfl_xor(xf0, 32, 64);
    xf1 += __shfl_xor(xf1, 16, 64); xf1 += __shfl_xor(xf1, 32, 64);
    if (lane < 16) { xfp[w][0][lane] = xf0; xfp[w][1][lane] = xf1; }
    __syncthreads();
    if (tid < 64) {
        const int strip = tid >> 4, col = tid & 15;
        const int mhh = strip >> 1, idx = strip & 1;
        float s = xfp[mhh][idx][col] + xfp[mhh + 2][idx][col]
                + xfp[mhh + 4][idx][col] + xfp[mhh + 6][idx][col];
        sc[m0 + strip * 16 + col] = s;
    }
}

// ============ k_att: MFMA-sum tanh logits + softmax + einsum + L2 ============
// blocks: b = bid/100, nq = (bid/25)%4, qg = bid%25; wave w -> q = qg*8+w.
__global__ __launch_bounds__(512)
void k_att(const float* __restrict__ Sf, const float* __restrict__ Qf,
           const float* __restrict__ S, const float* __restrict__ Q,
           const float* __restrict__ sc, const float* __restrict__ convf_b,
           float* __restrict__ out) {
    __shared__ __align__(16) _Float16 SfT[32 * 264];   // 16896 B
    __shared__ __align__(16) float Lw[8][32];          //  1024 B
    __shared__ __align__(16) float Qs[8][256];         //  8192 B
    const int bid = blockIdx.x, tid = threadIdx.x;
    const int lane = tid & 63;
    const int w = __builtin_amdgcn_readfirstlane(tid >> 6);   // 0..7
    const int b = bid / 100;
    const int nq = (bid / 25) & 3;
    const int qg = bid % 25;
    const int q = qg * 8 + w;
    const int n0 = nq * 5;
    const int ncl = lane & 15;
    const int g4 = lane >> 4;
    const int kg8 = g4 * 8;
    const float LOG2E = 1.4426950408889634f;
    const float bf0 = convf_b[0];

    // stage 25 Sf rows as f16, zero-padded to [32][264]
    const float* sfb = Sf + (size_t)(b * 100 + n0 * 5) * DD;
    for (int e = tid; e < 32 * 132; e += 512) {
        int row = e / 132, c2 = e - row * 132;
        unsigned int u = 0u;
        if (row < 25 && c2 <= 114) {
            float2 v = *(const float2*)&sfb[row * DD + 2 * c2];
            u = pk2(v.x, v.y);
        }
        *(unsigned int*)&SfT[row * 264 + 2 * c2] = u;
    }
    // stage the 8 Qf rows (zero pad cols >= 230)
    for (int e = tid; e < 8 * 256; e += 512) {
        int row = e >> 8, col = e & 255;
        float v = 0.f;
        if (col < DD) v = Qf[(size_t)(b * NQ + qg * 8 + row) * QST + col];
        Qs[row][col] = v;
    }
    __syncthreads();

    // ---- part 1: L[idx] = sum_d tanh(Sf*Qf) via MFMA ones-reduction ----
    f16x8 ones;
#pragma unroll
    for (int j = 0; j < 8; j++) ones[j] = (_Float16)1.f;
    f32x4 acc0 = {0.f, 0.f, 0.f, 0.f}, acc1 = {0.f, 0.f, 0.f, 0.f};

    for (int ks = 0; ks < 8; ks++) {
        f32x4 qa = *(const f32x4*)&Qs[w][ks * 32 + kg8];
        f32x4 qb = *(const f32x4*)&Qs[w][ks * 32 + kg8 + 4];
        float qv[8];
#pragma unroll
        for (int j = 0; j < 4; j++) { qv[j] = qa[j]; qv[4 + j] = qb[j]; }
#pragma unroll
        for (int t = 0; t < 2; t++) {
            f16x8 s8 = *(const f16x8*)&SfT[(t * 16 + ncl) * 264 + ks * 32 + kg8];
            f16x8 vf;
#pragma unroll
            for (int j = 0; j < 8; j++) {
                float x = (float)s8[j] * qv[j];
                float e = __builtin_amdgcn_exp2f(x);
                float v = 1.f - 2.f * __builtin_amdgcn_rcpf(e + 1.f);
                vf[j] = (_Float16)v;
            }
            if (t == 0) acc0 = __builtin_amdgcn_mfma_f32_16x16x32_f16(vf, ones, acc0, 0, 0, 0);
            else        acc1 = __builtin_amdgcn_mfma_f32_16x16x32_f16(vf, ones, acc1, 0, 0, 0);
        }
    }
    if (ncl == 0) {
        *(f32x4*)&Lw[w][g4 * 4] = acc0;
        *(f32x4*)&Lw[w][16 + g4 * 4] = acc1;
    }
    // same-wave produce/consume (compiler inserts lgkmcnt)

    // ---- part 2: softmax(K) + einsum + weighted L2 for this block's 5 n's ----
    float qr[4];
    const float* qp = Q + (size_t)(b * NQ + q) * DD;
#pragma unroll
    for (int i = 0; i < 4; i++) {
        int d = lane + 64 * i;
        qr[i] = (d < DD) ? qp[d] : 0.f;
    }
    for (int nl = 0; nl < 5; nl++) {
        const float* lp = &Lw[w][nl * 5];
        float v0 = lp[0], v1 = lp[1], v2 = lp[2], v3 = lp[3], v4 = lp[4];
        float m = fmaxf(fmaxf(fmaxf(v0, v1), fmaxf(v2, v3)), v4);
        float e0 = __builtin_amdgcn_exp2f((v0 - m) * LOG2E);
        float e1 = __builtin_amdgcn_exp2f((v1 - m) * LOG2E);
        float e2 = __builtin_amdgcn_exp2f((v2 - m) * LOG2E);
        float e3 = __builtin_amdgcn_exp2f((v3 - m) * LOG2E);
        float e4 = __builtin_amdgcn_exp2f((v4 - m) * LOG2E);
        float inv = __builtin_amdgcn_rcpf(e0 + e1 + e2 + e3 + e4);
        float a0 = e0 * inv, a1 = e1 * inv, a2 = e2 * inv, a3 = e3 * inv, a4 = e4 * inv;
        const int n = n0 + nl;
        const float* spn = S + (size_t)(b * NN + n) * KK * DD;
        const float* s0 = sc + (size_t)(b * NN + n) * DD;
        float acc2 = 0.f;
#pragma unroll
        for (int i = 0; i < 4; i++) {
            int d = lane + 64 * i;
            if (d < DD) {
                float rep = a0 * spn[d] + a1 * spn[DD + d] + a2 * spn[2 * DD + d]
                          + a3 * spn[3 * DD + d] + a4 * spn[4 * DD + d];
                float df = rep - qr[i];
                float scw = fmaxf(s0[d] + bf0, 0.f) * 700.f;
                acc2 = fmaf(df * df, scw, acc2);
            }
        }
#pragma unroll
        for (int off = 32; off > 0; off >>= 1) acc2 += __shfl_xor(acc2, off, 64);
        if (lane == 0) out[((size_t)b * NQ + q) * NN + n] = -acc2;
    }
}

extern "C" void kernel_launch(void* const* d_in, const int* in_sizes, int n_in,
                              void* d_out, int out_size, void* d_ws, size_t ws_size,
                              hipStream_t stream) {
    const float* S       = (const float*)d_in[0];
    const float* Q       = (const float*)d_in[1];
    const float* fc_w    = (const float*)d_in[2];
    const float* fc_b    = (const float*)d_in[3];
    const float* conv1_w = (const float*)d_in[4];
    const float* conv1_b = (const float*)d_in[5];
    const float* conv2_w = (const float*)d_in[6];
    const float* conv2_b = (const float*)d_in[7];
    const float* convf_w = (const float*)d_in[8];
    const float* convf_b = (const float*)d_in[9];
    float* out = (float*)d_out;

    float* ws = (float*)d_ws;
    float* Sf  = ws;                               // 184000 dwords
    float* Qf  = Sf + 184000;                      // 409600 (1600 x 256)
    float* sc  = Qf + 409600;                      // 36800
    _Float16* Bp  = (_Float16*)(sc + 36800);       // 51200 f16
    _Float16* Bfc = Bp + 51200;                    // 61440 f16
    float2* tblg  = (float2*)(Bfc + 61440);        // 640 dw

    k_pre<<<NB_BFC + NB_BP + NB_CP, 256, 0, stream>>>(
        fc_w, conv2_w, conv2_b, convf_w, Bfc, Bp, tblg,
        S, out + (size_t)BB * NQ * NN);
    k_main<<<NB_CONV + NB_FC2, 512, 0, stream>>>(
        S, Q, conv1_w, conv1_b, Bp, Bfc, tblg, sc, fc_b, Sf, Qf);
    k_att<<<NB_ATT, 512, 0, stream>>>(
        Sf, Qf, S, Q, sc, convf_b, out);
}

// Round 20
// 62.559 us; speedup vs baseline: 1.1905x; 1.0567x over previous
//
#include <hip/hip_runtime.h>
#include <hip/hip_bf16.h>

typedef _Float16 f16x8 __attribute__((ext_vector_type(8)));
typedef float f32x4 __attribute__((ext_vector_type(4)));

#define BB 8
#define NN 20
#define KK 5
#define DD 230
#define NQ 200
#define QST 256   // padded Qf row stride (dwords)

#define NB_BFC 240   // build Bfc: 61440 f16 fc fragments
#define NB_BP  200   // build Bp: 51200 f16 conv fragments + tblg
#define NB_CP  180   // 46000 float4 S-copy (256 thr)
#define NB_CONV 575  // conv M-tiles (64 rows)
#define NB_FC2 38    // fc M-tiles (64 rows)
#define NB_ATT 800   // 8 b x 4 n-quarters x 25 q-groups

static __device__ __forceinline__ unsigned int pk2(float a, float b) {
    union { __fp16 h[2] __attribute__((aligned(4))); unsigned int u; } v;
    v.h[0] = (__fp16)a; v.h[1] = (__fp16)b; return v.u;
}

// ============ k_pre: fragment-packed Bfc + Bp + tables + S copy ============
__global__ void k_pre(const float* __restrict__ fc_w,
                      const float* __restrict__ w2, const float* __restrict__ b2,
                      const float* __restrict__ wf,
                      _Float16* __restrict__ Bfc, _Float16* __restrict__ Bp,
                      float2* __restrict__ tblg,
                      const float* __restrict__ S, float* __restrict__ Scopy) {
    const int bid = blockIdx.x, tid = threadIdx.x;
    if (bid < NB_BFC) {
        int g = bid * 256 + tid;             // < 61440
        int kg = g & 31;
        int ncl = (g >> 5) & 15;
        int tk = g >> 9;                     // nt*8+ks
        int nt = tk >> 3, ks = tk & 7;
        int n = nt * 16 + ncl, k = ks * 32 + kg;
        float val = (n < DD && k < DD) ? fc_w[n * DD + k] : 0.f;
        Bfc[g] = (_Float16)val;
    } else if (bid < NB_BFC + NB_BP) {
        int g = (bid - NB_BFC) * 256 + tid;  // < 51200
        int kg = g & 31;
        int ncl = (g >> 5) & 15;
        int tk = g >> 9;                     // nt*5+ks
        int nt = tk / 5, ks = tk - nt * 5;
        int n = nt * 16 + ncl, k = ks * 32 + kg;
        int o = n / 5, i = n % 5;
        int c = k / 5, j = k - c * 5;
        int t = j - i + 2;
        float val = (t >= 0 && t < 5) ? w2[(o * 32 + c) * 5 + t] : 0.f;
        Bp[g] = (_Float16)val;
        if (g < 320) {
            int o2 = g / 5, i2 = g % 5;
            tblg[g] = make_float2(b2[o2], wf[o2 * 5 + i2]);
        }
    } else {
        int g = (bid - NB_BFC - NB_BP) * 256 + tid;
        if (g < 46000) ((float4*)Scopy)[g] = ((const float4*)S)[g];
    }
}

// ============ k_main: conv-as-MFMA (0..574) + fc-as-MFMA (575..612) ============
__global__ __launch_bounds__(512)
void k_main(const float* __restrict__ S, const float* __restrict__ Q,
            const float* __restrict__ w1, const float* __restrict__ b1,
            const _Float16* __restrict__ Bp, const _Float16* __restrict__ Bfc,
            const float2* __restrict__ tblg, float* __restrict__ sc,
            const float* __restrict__ fc_b,
            float* __restrict__ Sf, float* __restrict__ Qf) {
    __shared__ __align__(16) _Float16 XU[64 * 264];
    __shared__ float xfp[8][2][16];
    const int bid = blockIdx.x, tid = threadIdx.x;
    const int lane = tid & 63;
    const int w = __builtin_amdgcn_readfirstlane(tid >> 6);
    const int ncl = lane & 15;
    const int kg8 = (lane >> 4) * 8;
    const int g4 = lane >> 4;

    if (bid >= NB_CONV) {
        // ---- fc GEMM: 64 rows ----
        const int m0 = (bid - NB_CONV) * 64;
        for (int e = tid; e < 64 * 58; e += 512) {
            int row = e / 58, c4 = e - row * 58;
            int grow = m0 + row;
            float4 v = make_float4(0.f, 0.f, 0.f, 0.f);
            if (grow < 2400) {
                const float* inp = (grow < 800) ? S + (size_t)grow * DD
                                                : Q + (size_t)(grow - 800) * DD;
                if (c4 < 57) v = *(const float4*)&inp[c4 * 4];
                else { v.x = inp[228]; v.y = inp[229]; }
            }
            _Float16* xp = &XU[row * 264 + c4 * 4];
            xp[0] = (_Float16)v.x; xp[1] = (_Float16)v.y;
            xp[2] = (_Float16)v.z; xp[3] = (_Float16)v.w;
        }
        for (int e = tid; e < 64 * 16; e += 512) {
            int row = e >> 4, cc = 232 + (e & 15) * 2;
            *(unsigned int*)&XU[row * 264 + cc] = 0u;
        }
        __syncthreads();

        const int msub = w & 3;
        const int ngrp = w >> 2;
        f16x8 af[8];
#pragma unroll
        for (int ks = 0; ks < 8; ks++)
            af[ks] = *(const f16x8*)&XU[(msub * 16 + ncl) * 264 + ks * 32 + kg8];

        const int nt0 = ngrp * 8;
        const int ntn = ngrp ? 7 : 8;
        for (int ti = 0; ti < ntn; ti++) {
            const int nt = nt0 + ti;
            const _Float16* bp = Bfc + ((size_t)nt * 8 * 16) * 32;
            f32x4 a = {0.f, 0.f, 0.f, 0.f};
#pragma unroll
            for (int ks = 0; ks < 8; ks++) {
                f16x8 br = *(const f16x8*)&bp[(ks * 16 + ncl) * 32 + kg8];
                a = __builtin_amdgcn_mfma_f32_16x16x32_f16(af[ks], br, a, 0, 0, 0);
            }
            const int n = nt * 16 + ncl;
            const float bias = fc_b[n < DD ? n : DD - 1];
            if (n < DD) {
#pragma unroll
                for (int r = 0; r < 4; r++) {
                    int grow = m0 + msub * 16 + g4 * 4 + r;
                    if (grow < 800)
                        Sf[(size_t)grow * DD + n] = (a[r] + bias) * 2.8853900817779268f;
                    else if (grow < 2400)
                        Qf[(size_t)(grow - 800) * QST + n] = a[r] + bias;
                }
            }
        }
        return;
    }

    // ---- conv: 64 M-rows; wave w = (mh = w&1, gq = w>>1 -> tiles gq*5..+4) ----
    const int m0 = bid * 64;
    {
        const int m = m0 + lane;
        const int img = m / DD;
        const int d = m - img * DD;
        const float* sp = S + (size_t)img * KK * DD + d;
        float in5[5];
#pragma unroll
        for (int j = 0; j < 5; j++) in5[j] = sp[j * DD];
#pragma unroll
        for (int cc = 0; cc < 4; cc++) {
            int c = w * 4 + cc;
            float wl[5];
#pragma unroll
            for (int t = 0; t < 5; t++) wl[t] = w1[c * 5 + t];
            float bb = b1[c];
#pragma unroll
            for (int i = 0; i < 5; i++) {
                float a = bb;
#pragma unroll
                for (int t = 0; t < 5; t++) {
                    int j = i + t - 2;
                    if (j >= 0 && j < 5) a = fmaf(wl[t], in5[j], a);
                }
                XU[lane * 168 + c * 5 + i] = (_Float16)fmaxf(a, 0.f);
            }
        }
    }
    __syncthreads();

    const int mh = w & 1;
    const int gq = w >> 1;
    f16x8 af0[5], af1[5];
#pragma unroll
    for (int ks = 0; ks < 5; ks++) {
        af0[ks] = *(const f16x8*)&XU[((mh * 2 + 0) * 16 + ncl) * 168 + ks * 32 + kg8];
        af1[ks] = *(const f16x8*)&XU[((mh * 2 + 1) * 16 + ncl) * 168 + ks * 32 + kg8];
    }

    float xf0 = 0.f, xf1 = 0.f;
#pragma unroll
    for (int t5 = 0; t5 < 5; t5++) {
        const int nt = gq * 5 + t5;
        const _Float16* bp = Bp + ((size_t)nt * 5 * 16) * 32;
        f16x8 br[5];
#pragma unroll
        for (int ks = 0; ks < 5; ks++)
            br[ks] = *(const f16x8*)&bp[(ks * 16 + ncl) * 32 + kg8];
        f32x4 a0 = {0.f, 0.f, 0.f, 0.f}, a1 = {0.f, 0.f, 0.f, 0.f};
#pragma unroll
        for (int ks = 0; ks < 5; ks++) {
            a0 = __builtin_amdgcn_mfma_f32_16x16x32_f16(br[ks], af0[ks], a0, 0, 0, 0);
            a1 = __builtin_amdgcn_mfma_f32_16x16x32_f16(br[ks], af1[ks], a1, 0, 0, 0);
        }
        float2 tb[4];
#pragma unroll
        for (int r = 0; r < 4; r++) tb[r] = tblg[nt * 16 + g4 * 4 + r];
#pragma unroll
        for (int r = 0; r < 4; r++) {
            xf0 = fmaf(fmaxf(a0[r] + tb[r].x, 0.f), tb[r].y, xf0);
            xf1 = fmaf(fmaxf(a1[r] + tb[r].x, 0.f), tb[r].y, xf1);
        }
    }
    xf0 += __shfl_xor(xf0, 16, 64); xf0 += __shfl_xor(xf0, 32, 64);
    xf1 += __shfl_xor(xf1, 16, 64); xf1 += __shfl_xor(xf1, 32, 64);
    if (lane < 16) { xfp[w][0][lane] = xf0; xfp[w][1][lane] = xf1; }
    __syncthreads();
    if (tid < 64) {
        const int strip = tid >> 4, col = tid & 15;
        const int mhh = strip >> 1, idx = strip & 1;
        float s = xfp[mhh][idx][col] + xfp[mhh + 2][idx][col]
                + xfp[mhh + 4][idx][col] + xfp[mhh + 6][idx][col];
        sc[m0 + strip * 16 + col] = s;
    }
}

// ============ k_att: MFMA-sum tanh logits + softmax + einsum + L2 ============
// XCD-swizzled: logical bid = (phys&7)*100 + phys>>3 (800 = 8*100, bijective).
// All 25 qg-blocks of one (b,nq) share a phys%8 class -> same XCD L2.
__global__ __launch_bounds__(512)
void k_att(const float* __restrict__ Sf, const float* __restrict__ Qf,
           const float* __restrict__ S, const float* __restrict__ Q,
           const float* __restrict__ sc, const float* __restrict__ convf_b,
           float* __restrict__ out) {
    __shared__ __align__(16) _Float16 SfT[32 * 264];   // 16896 B
    __shared__ __align__(16) float Lw[8][32];          //  1024 B
    __shared__ __align__(16) float Qs[8][256];         //  8192 B
    const int phys = blockIdx.x, tid = threadIdx.x;
    const int bid = (phys & 7) * 100 + (phys >> 3);    // bijective XCD swizzle
    const int lane = tid & 63;
    const int w = __builtin_amdgcn_readfirstlane(tid >> 6);   // 0..7
    const int b = bid / 100;
    const int nq = (bid / 25) & 3;
    const int qg = bid % 25;
    const int q = qg * 8 + w;
    const int n0 = nq * 5;
    const int ncl = lane & 15;
    const int g4 = lane >> 4;
    const int kg8 = g4 * 8;
    const float LOG2E = 1.4426950408889634f;
    const float bf0 = convf_b[0];

    // stage 25 Sf rows as f16, zero-padded to [32][264]
    const float* sfb = Sf + (size_t)(b * 100 + n0 * 5) * DD;
    for (int e = tid; e < 32 * 132; e += 512) {
        int row = e / 132, c2 = e - row * 132;
        unsigned int u = 0u;
        if (row < 25 && c2 <= 114) {
            float2 v = *(const float2*)&sfb[row * DD + 2 * c2];
            u = pk2(v.x, v.y);
        }
        *(unsigned int*)&SfT[row * 264 + 2 * c2] = u;
    }
    // stage the 8 Qf rows (zero pad cols >= 230)
    for (int e = tid; e < 8 * 256; e += 512) {
        int row = e >> 8, col = e & 255;
        float v = 0.f;
        if (col < DD) v = Qf[(size_t)(b * NQ + qg * 8 + row) * QST + col];
        Qs[row][col] = v;
    }
    __syncthreads();

    // ---- part 1: L[idx] = sum_d tanh(Sf*Qf) via MFMA ones-reduction ----
    f16x8 ones;
#pragma unroll
    for (int j = 0; j < 8; j++) ones[j] = (_Float16)1.f;
    f32x4 acc0 = {0.f, 0.f, 0.f, 0.f}, acc1 = {0.f, 0.f, 0.f, 0.f};

    for (int ks = 0; ks < 8; ks++) {
        f32x4 qa = *(const f32x4*)&Qs[w][ks * 32 + kg8];
        f32x4 qb = *(const f32x4*)&Qs[w][ks * 32 + kg8 + 4];
        float qv[8];
#pragma unroll
        for (int j = 0; j < 4; j++) { qv[j] = qa[j]; qv[4 + j] = qb[j]; }
#pragma unroll
        for (int t = 0; t < 2; t++) {
            f16x8 s8 = *(const f16x8*)&SfT[(t * 16 + ncl) * 264 + ks * 32 + kg8];
            f16x8 vf;
#pragma unroll
            for (int j = 0; j < 8; j++) {
                float x = (float)s8[j] * qv[j];
                float e = __builtin_amdgcn_exp2f(x);
                float v = 1.f - 2.f * __builtin_amdgcn_rcpf(e + 1.f);
                vf[j] = (_Float16)v;
            }
            if (t == 0) acc0 = __builtin_amdgcn_mfma_f32_16x16x32_f16(vf, ones, acc0, 0, 0, 0);
            else        acc1 = __builtin_amdgcn_mfma_f32_16x16x32_f16(vf, ones, acc1, 0, 0, 0);
        }
    }
    if (ncl == 0) {
        *(f32x4*)&Lw[w][g4 * 4] = acc0;
        *(f32x4*)&Lw[w][16 + g4 * 4] = acc1;
    }
    // same-wave produce/consume (compiler inserts lgkmcnt)

    // ---- part 2: softmax(K) + einsum + weighted L2 for this block's 5 n's ----
    float qr[4];
    const float* qp = Q + (size_t)(b * NQ + q) * DD;
#pragma unroll
    for (int i = 0; i < 4; i++) {
        int d = lane + 64 * i;
        qr[i] = (d < DD) ? qp[d] : 0.f;
    }
    for (int nl = 0; nl < 5; nl++) {
        const float* lp = &Lw[w][nl * 5];
        float v0 = lp[0], v1 = lp[1], v2 = lp[2], v3 = lp[3], v4 = lp[4];
        float m = fmaxf(fmaxf(fmaxf(v0, v1), fmaxf(v2, v3)), v4);
        float e0 = __builtin_amdgcn_exp2f((v0 - m) * LOG2E);
        float e1 = __builtin_amdgcn_exp2f((v1 - m) * LOG2E);
        float e2 = __builtin_amdgcn_exp2f((v2 - m) * LOG2E);
        float e3 = __builtin_amdgcn_exp2f((v3 - m) * LOG2E);
        float e4 = __builtin_amdgcn_exp2f((v4 - m) * LOG2E);
        float inv = __builtin_amdgcn_rcpf(e0 + e1 + e2 + e3 + e4);
        float a0 = e0 * inv, a1 = e1 * inv, a2 = e2 * inv, a3 = e3 * inv, a4 = e4 * inv;
        const int n = n0 + nl;
        const float* spn = S + (size_t)(b * NN + n) * KK * DD;
        const float* s0 = sc + (size_t)(b * NN + n) * DD;
        float acc2 = 0.f;
#pragma unroll
        for (int i = 0; i < 4; i++) {
            int d = lane + 64 * i;
            if (d < DD) {
                float rep = a0 * spn[d] + a1 * spn[DD + d] + a2 * spn[2 * DD + d]
                          + a3 * spn[3 * DD + d] + a4 * spn[4 * DD + d];
                float df = rep - qr[i];
                float scw = fmaxf(s0[d] + bf0, 0.f) * 700.f;
                acc2 = fmaf(df * df, scw, acc2);
            }
        }
#pragma unroll
        for (int off = 32; off > 0; off >>= 1) acc2 += __shfl_xor(acc2, off, 64);
        if (lane == 0) out[((size_t)b * NQ + q) * NN + n] = -acc2;
    }
}

extern "C" void kernel_launch(void* const* d_in, const int* in_sizes, int n_in,
                              void* d_out, int out_size, void* d_ws, size_t ws_size,
                              hipStream_t stream) {
    const float* S       = (const float*)d_in[0];
    const float* Q       = (const float*)d_in[1];
    const float* fc_w    = (const float*)d_in[2];
    const float* fc_b    = (const float*)d_in[3];
    const float* conv1_w = (const float*)d_in[4];
    const float* conv1_b = (const float*)d_in[5];
    const float* conv2_w = (const float*)d_in[6];
    const float* conv2_b = (const float*)d_in[7];
    const float* convf_w = (const float*)d_in[8];
    const float* convf_b = (const float*)d_in[9];
    float* out = (float*)d_out;

    float* ws = (float*)d_ws;
    float* Sf  = ws;                               // 184000 dwords
    float* Qf  = Sf + 184000;                      // 409600 (1600 x 256)
    float* sc  = Qf + 409600;                      // 36800
    _Float16* Bp  = (_Float16*)(sc + 36800);       // 51200 f16
    _Float16* Bfc = Bp + 51200;                    // 61440 f16
    float2* tblg  = (float2*)(Bfc + 61440);        // 640 dw

    k_pre<<<NB_BFC + NB_BP + NB_CP, 256, 0, stream>>>(
        fc_w, conv2_w, conv2_b, convf_w, Bfc, Bp, tblg,
        S, out + (size_t)BB * NQ * NN);
    k_main<<<NB_CONV + NB_FC2, 512, 0, stream>>>(
        S, Q, conv1_w, conv1_b, Bp, Bfc, tblg, sc, fc_b, Sf, Qf);
    k_att<<<NB_ATT, 512, 0, stream>>>(
        Sf, Qf, S, Q, sc, convf_b, out);
}

// Round 21
// 61.898 us; speedup vs baseline: 1.2032x; 1.0107x over previous
//
#include <hip/hip_runtime.h>
#include <hip/hip_bf16.h>

typedef _Float16 f16x8 __attribute__((ext_vector_type(8)));
typedef float f32x4 __attribute__((ext_vector_type(4)));

#define BB 8
#define NN 20
#define KK 5
#define DD 230
#define NQ 200
#define QST 256   // padded Qf row stride (dwords)

#define NB_BFC 240   // build Bfc: 61440 f16 fc fragments
#define NB_BP  200   // build Bp: 51200 f16 conv fragments + tblg
#define NB_CP  180   // 46000 float4 S-copy (256 thr)
#define NB_CONV 575  // conv M-tiles (64 rows)
#define NB_FC2 38    // fc M-tiles (64 rows)
#define NB_ATT 800   // 8 b x 4 n-quarters x 25 q-groups

static __device__ __forceinline__ unsigned int pk2(float a, float b) {
    union { __fp16 h[2] __attribute__((aligned(4))); unsigned int u; } v;
    v.h[0] = (__fp16)a; v.h[1] = (__fp16)b; return v.u;
}

// ============ k_pre: fragment-packed Bfc + Bp + tables + S copy ============
__global__ void k_pre(const float* __restrict__ fc_w,
                      const float* __restrict__ w2, const float* __restrict__ b2,
                      const float* __restrict__ wf,
                      _Float16* __restrict__ Bfc, _Float16* __restrict__ Bp,
                      float2* __restrict__ tblg,
                      const float* __restrict__ S, float* __restrict__ Scopy) {
    const int bid = blockIdx.x, tid = threadIdx.x;
    if (bid < NB_BFC) {
        int g = bid * 256 + tid;             // < 61440
        int kg = g & 31;
        int ncl = (g >> 5) & 15;
        int tk = g >> 9;                     // nt*8+ks
        int nt = tk >> 3, ks = tk & 7;
        int n = nt * 16 + ncl, k = ks * 32 + kg;
        float val = (n < DD && k < DD) ? fc_w[n * DD + k] : 0.f;
        Bfc[g] = (_Float16)val;
    } else if (bid < NB_BFC + NB_BP) {
        int g = (bid - NB_BFC) * 256 + tid;  // < 51200
        int kg = g & 31;
        int ncl = (g >> 5) & 15;
        int tk = g >> 9;                     // nt*5+ks
        int nt = tk / 5, ks = tk - nt * 5;
        int n = nt * 16 + ncl, k = ks * 32 + kg;
        int o = n / 5, i = n % 5;
        int c = k / 5, j = k - c * 5;
        int t = j - i + 2;
        float val = (t >= 0 && t < 5) ? w2[(o * 32 + c) * 5 + t] : 0.f;
        Bp[g] = (_Float16)val;
        if (g < 320) {
            int o2 = g / 5, i2 = g % 5;
            tblg[g] = make_float2(b2[o2], wf[o2 * 5 + i2]);
        }
    } else {
        int g = (bid - NB_BFC - NB_BP) * 256 + tid;
        if (g < 46000) ((float4*)Scopy)[g] = ((const float4*)S)[g];
    }
}

// ============ k_main: conv-as-MFMA (0..574) + fc-as-MFMA (575..612) ============
__global__ __launch_bounds__(512)
void k_main(const float* __restrict__ S, const float* __restrict__ Q,
            const float* __restrict__ w1, const float* __restrict__ b1,
            const _Float16* __restrict__ Bp, const _Float16* __restrict__ Bfc,
            const float2* __restrict__ tblg, float* __restrict__ sc,
            const float* __restrict__ fc_b,
            float* __restrict__ Sf, float* __restrict__ Qf) {
    __shared__ __align__(16) _Float16 XU[64 * 264];
    __shared__ float xfp[8][2][16];
    const int bid = blockIdx.x, tid = threadIdx.x;
    const int lane = tid & 63;
    const int w = __builtin_amdgcn_readfirstlane(tid >> 6);
    const int ncl = lane & 15;
    const int kg8 = (lane >> 4) * 8;
    const int g4 = lane >> 4;

    if (bid >= NB_CONV) {
        // ---- fc GEMM: 64 rows ----
        const int m0 = (bid - NB_CONV) * 64;
        for (int e = tid; e < 64 * 58; e += 512) {
            int row = e / 58, c4 = e - row * 58;
            int grow = m0 + row;
            float4 v = make_float4(0.f, 0.f, 0.f, 0.f);
            if (grow < 2400) {
                const float* inp = (grow < 800) ? S + (size_t)grow * DD
                                                : Q + (size_t)(grow - 800) * DD;
                if (c4 < 57) v = *(const float4*)&inp[c4 * 4];
                else { v.x = inp[228]; v.y = inp[229]; }
            }
            _Float16* xp = &XU[row * 264 + c4 * 4];
            xp[0] = (_Float16)v.x; xp[1] = (_Float16)v.y;
            xp[2] = (_Float16)v.z; xp[3] = (_Float16)v.w;
        }
        for (int e = tid; e < 64 * 16; e += 512) {
            int row = e >> 4, cc = 232 + (e & 15) * 2;
            *(unsigned int*)&XU[row * 264 + cc] = 0u;
        }
        __syncthreads();

        const int msub = w & 3;
        const int ngrp = w >> 2;
        f16x8 af[8];
#pragma unroll
        for (int ks = 0; ks < 8; ks++)
            af[ks] = *(const f16x8*)&XU[(msub * 16 + ncl) * 264 + ks * 32 + kg8];

        const int nt0 = ngrp * 8;
        const int ntn = ngrp ? 7 : 8;
        for (int ti = 0; ti < ntn; ti++) {
            const int nt = nt0 + ti;
            const _Float16* bp = Bfc + ((size_t)nt * 8 * 16) * 32;
            f32x4 a = {0.f, 0.f, 0.f, 0.f};
#pragma unroll
            for (int ks = 0; ks < 8; ks++) {
                f16x8 br = *(const f16x8*)&bp[(ks * 16 + ncl) * 32 + kg8];
                a = __builtin_amdgcn_mfma_f32_16x16x32_f16(af[ks], br, a, 0, 0, 0);
            }
            const int n = nt * 16 + ncl;
            const float bias = fc_b[n < DD ? n : DD - 1];
            if (n < DD) {
#pragma unroll
                for (int r = 0; r < 4; r++) {
                    int grow = m0 + msub * 16 + g4 * 4 + r;
                    if (grow < 800)
                        Sf[(size_t)grow * DD + n] = (a[r] + bias) * 2.8853900817779268f;
                    else if (grow < 2400)
                        Qf[(size_t)(grow - 800) * QST + n] = a[r] + bias;
                }
            }
        }
        return;
    }

    // ---- conv: 64 M-rows; wave w = (mh = w&1, gq = w>>1 -> tiles gq*5..+4) ----
    const int m0 = bid * 64;
    {
        const int m = m0 + lane;
        const int img = m / DD;
        const int d = m - img * DD;
        const float* sp = S + (size_t)img * KK * DD + d;
        float in5[5];
#pragma unroll
        for (int j = 0; j < 5; j++) in5[j] = sp[j * DD];
#pragma unroll
        for (int cc = 0; cc < 4; cc++) {
            int c = w * 4 + cc;
            float wl[5];
#pragma unroll
            for (int t = 0; t < 5; t++) wl[t] = w1[c * 5 + t];
            float bb = b1[c];
#pragma unroll
            for (int i = 0; i < 5; i++) {
                float a = bb;
#pragma unroll
                for (int t = 0; t < 5; t++) {
                    int j = i + t - 2;
                    if (j >= 0 && j < 5) a = fmaf(wl[t], in5[j], a);
                }
                XU[lane * 168 + c * 5 + i] = (_Float16)fmaxf(a, 0.f);
            }
        }
    }
    __syncthreads();

    const int mh = w & 1;
    const int gq = w >> 1;
    f16x8 af0[5], af1[5];
#pragma unroll
    for (int ks = 0; ks < 5; ks++) {
        af0[ks] = *(const f16x8*)&XU[((mh * 2 + 0) * 16 + ncl) * 168 + ks * 32 + kg8];
        af1[ks] = *(const f16x8*)&XU[((mh * 2 + 1) * 16 + ncl) * 168 + ks * 32 + kg8];
    }

    float xf0 = 0.f, xf1 = 0.f;
#pragma unroll
    for (int t5 = 0; t5 < 5; t5++) {
        const int nt = gq * 5 + t5;
        const _Float16* bp = Bp + ((size_t)nt * 5 * 16) * 32;
        f16x8 br[5];
#pragma unroll
        for (int ks = 0; ks < 5; ks++)
            br[ks] = *(const f16x8*)&bp[(ks * 16 + ncl) * 32 + kg8];
        f32x4 a0 = {0.f, 0.f, 0.f, 0.f}, a1 = {0.f, 0.f, 0.f, 0.f};
#pragma unroll
        for (int ks = 0; ks < 5; ks++) {
            a0 = __builtin_amdgcn_mfma_f32_16x16x32_f16(br[ks], af0[ks], a0, 0, 0, 0);
            a1 = __builtin_amdgcn_mfma_f32_16x16x32_f16(br[ks], af1[ks], a1, 0, 0, 0);
        }
        float2 tb[4];
#pragma unroll
        for (int r = 0; r < 4; r++) tb[r] = tblg[nt * 16 + g4 * 4 + r];
#pragma unroll
        for (int r = 0; r < 4; r++) {
            xf0 = fmaf(fmaxf(a0[r] + tb[r].x, 0.f), tb[r].y, xf0);
            xf1 = fmaf(fmaxf(a1[r] + tb[r].x, 0.f), tb[r].y, xf1);
        }
    }
    xf0 += __shfl_xor(xf0, 16, 64); xf0 += __shfl_xor(xf0, 32, 64);
    xf1 += __shfl_xor(xf1, 16, 64); xf1 += __shfl_xor(xf1, 32, 64);
    if (lane < 16) { xfp[w][0][lane] = xf0; xfp[w][1][lane] = xf1; }
    __syncthreads();
    if (tid < 64) {
        const int strip = tid >> 4, col = tid & 15;
        const int mhh = strip >> 1, idx = strip & 1;
        float s = xfp[mhh][idx][col] + xfp[mhh + 2][idx][col]
                + xfp[mhh + 4][idx][col] + xfp[mhh + 6][idx][col];
        sc[m0 + strip * 16 + col] = s;
    }
}

// ============ k_att: MFMA-sum tanh logits + softmax + einsum + L2 ============
// XCD-swizzled: logical bid = (phys&7)*100 + phys>>3 (800 = 8*100, bijective).
__global__ __launch_bounds__(512)
void k_att(const float* __restrict__ Sf, const float* __restrict__ Qf,
           const float* __restrict__ S, const float* __restrict__ Q,
           const float* __restrict__ sc, const float* __restrict__ convf_b,
           float* __restrict__ out) {
    __shared__ __align__(16) _Float16 SfT[32 * 264];   // 16896 B
    __shared__ __align__(16) float Lw[8][32];          //  1024 B
    __shared__ __align__(16) float Qs[8][256];         //  8192 B
    const int phys = blockIdx.x, tid = threadIdx.x;
    const int bid = (phys & 7) * 100 + (phys >> 3);    // bijective XCD swizzle
    const int lane = tid & 63;
    const int w = __builtin_amdgcn_readfirstlane(tid >> 6);   // 0..7
    const int b = bid / 100;
    const int nq = (bid / 25) & 3;
    const int qg = bid % 25;
    const int q = qg * 8 + w;
    const int n0 = nq * 5;
    const int ncl = lane & 15;
    const int g4 = lane >> 4;
    const int kg8 = g4 * 8;
    const float LOG2E = 1.4426950408889634f;
    const float bf0 = convf_b[0];

    // stage 25 Sf rows as f16, zero-padded to [32][264]
    const float* sfb = Sf + (size_t)(b * 100 + n0 * 5) * DD;
    for (int e = tid; e < 32 * 132; e += 512) {
        int row = e / 132, c2 = e - row * 132;
        unsigned int u = 0u;
        if (row < 25 && c2 <= 114) {
            float2 v = *(const float2*)&sfb[row * DD + 2 * c2];
            u = pk2(v.x, v.y);
        }
        *(unsigned int*)&SfT[row * 264 + 2 * c2] = u;
    }
    // stage the 8 Qf rows (zero pad cols >= 230)
    for (int e = tid; e < 8 * 256; e += 512) {
        int row = e >> 8, col = e & 255;
        float v = 0.f;
        if (col < DD) v = Qf[(size_t)(b * NQ + qg * 8 + row) * QST + col];
        Qs[row][col] = v;
    }
    __syncthreads();

    // ---- part 1: L[idx] = sum_d tanh(Sf*Qf) via MFMA ones-reduction ----
    f16x8 ones;
#pragma unroll
    for (int j = 0; j < 8; j++) ones[j] = (_Float16)1.f;
    f32x4 acc0 = {0.f, 0.f, 0.f, 0.f}, acc1 = {0.f, 0.f, 0.f, 0.f};

    for (int ks = 0; ks < 8; ks++) {
        f32x4 qa = *(const f32x4*)&Qs[w][ks * 32 + kg8];
        f32x4 qb = *(const f32x4*)&Qs[w][ks * 32 + kg8 + 4];
        float qv[8];
#pragma unroll
        for (int j = 0; j < 4; j++) { qv[j] = qa[j]; qv[4 + j] = qb[j]; }
#pragma unroll
        for (int t = 0; t < 2; t++) {
            f16x8 s8 = *(const f16x8*)&SfT[(t * 16 + ncl) * 264 + ks * 32 + kg8];
            f16x8 vf;
#pragma unroll
            for (int j = 0; j < 8; j++) {
                float x = (float)s8[j] * qv[j];
                float e = __builtin_amdgcn_exp2f(x);
                float v = 1.f - 2.f * __builtin_amdgcn_rcpf(e + 1.f);
                vf[j] = (_Float16)v;
            }
            if (t == 0) acc0 = __builtin_amdgcn_mfma_f32_16x16x32_f16(vf, ones, acc0, 0, 0, 0);
            else        acc1 = __builtin_amdgcn_mfma_f32_16x16x32_f16(vf, ones, acc1, 0, 0, 0);
        }
    }
    if (ncl == 0) {
        *(f32x4*)&Lw[w][g4 * 4] = acc0;
        *(f32x4*)&Lw[w][16 + g4 * 4] = acc1;
    }
    // same-wave produce/consume (compiler inserts lgkmcnt)

    // ---- part 2: softmax(K) + einsum + weighted L2, branch-free (clamp+mask) ----
    // dc = clamped d, msk = exact 0/1; masked lanes contribute exactly 0.
    int dcl[4];
    float msk[4];
#pragma unroll
    for (int i = 0; i < 4; i++) {
        int d = lane + 64 * i;
        dcl[i] = d < DD ? d : DD - 1;
        msk[i] = d < DD ? 1.f : 0.f;
    }
    float qr[4];
    const float* qp = Q + (size_t)(b * NQ + q) * DD;
#pragma unroll
    for (int i = 0; i < 4; i++) qr[i] = qp[dcl[i]];

#pragma unroll
    for (int nl = 0; nl < 5; nl++) {
        const float* lp = &Lw[w][nl * 5];
        float v0 = lp[0], v1 = lp[1], v2 = lp[2], v3 = lp[3], v4 = lp[4];
        float m = fmaxf(fmaxf(fmaxf(v0, v1), fmaxf(v2, v3)), v4);
        float e0 = __builtin_amdgcn_exp2f((v0 - m) * LOG2E);
        float e1 = __builtin_amdgcn_exp2f((v1 - m) * LOG2E);
        float e2 = __builtin_amdgcn_exp2f((v2 - m) * LOG2E);
        float e3 = __builtin_amdgcn_exp2f((v3 - m) * LOG2E);
        float e4 = __builtin_amdgcn_exp2f((v4 - m) * LOG2E);
        float inv = __builtin_amdgcn_rcpf(e0 + e1 + e2 + e3 + e4);
        float a0 = e0 * inv, a1 = e1 * inv, a2 = e2 * inv, a3 = e3 * inv, a4 = e4 * inv;
        const int n = n0 + nl;
        const float* spn = S + (size_t)(b * NN + n) * KK * DD;
        const float* s0 = sc + (size_t)(b * NN + n) * DD;
        float acc2 = 0.f;
#pragma unroll
        for (int i = 0; i < 4; i++) {
            int d = dcl[i];
            float rep = a0 * spn[d] + a1 * spn[DD + d] + a2 * spn[2 * DD + d]
                      + a3 * spn[3 * DD + d] + a4 * spn[4 * DD + d];
            float df = rep - qr[i];
            float scw = fmaxf(s0[d] + bf0, 0.f) * 700.f * msk[i];
            acc2 = fmaf(df * df, scw, acc2);
        }
#pragma unroll
        for (int off = 32; off > 0; off >>= 1) acc2 += __shfl_xor(acc2, off, 64);
        if (lane == 0) out[((size_t)b * NQ + q) * NN + n] = -acc2;
    }
}

extern "C" void kernel_launch(void* const* d_in, const int* in_sizes, int n_in,
                              void* d_out, int out_size, void* d_ws, size_t ws_size,
                              hipStream_t stream) {
    const float* S       = (const float*)d_in[0];
    const float* Q       = (const float*)d_in[1];
    const float* fc_w    = (const float*)d_in[2];
    const float* fc_b    = (const float*)d_in[3];
    const float* conv1_w = (const float*)d_in[4];
    const float* conv1_b = (const float*)d_in[5];
    const float* conv2_w = (const float*)d_in[6];
    const float* conv2_b = (const float*)d_in[7];
    const float* convf_w = (const float*)d_in[8];
    const float* convf_b = (const float*)d_in[9];
    float* out = (float*)d_out;

    float* ws = (float*)d_ws;
    float* Sf  = ws;                               // 184000 dwords
    float* Qf  = Sf + 184000;                      // 409600 (1600 x 256)
    float* sc  = Qf + 409600;                      // 36800
    _Float16* Bp  = (_Float16*)(sc + 36800);       // 51200 f16
    _Float16* Bfc = Bp + 51200;                    // 61440 f16
    float2* tblg  = (float2*)(Bfc + 61440);        // 640 dw

    k_pre<<<NB_BFC + NB_BP + NB_CP, 256, 0, stream>>>(
        fc_w, conv2_w, conv2_b, convf_w, Bfc, Bp, tblg,
        S, out + (size_t)BB * NQ * NN);
    k_main<<<NB_CONV + NB_FC2, 512, 0, stream>>>(
        S, Q, conv1_w, conv1_b, Bp, Bfc, tblg, sc, fc_b, Sf, Qf);
    k_att<<<NB_ATT, 512, 0, stream>>>(
        Sf, Qf, S, Q, sc, convf_b, out);
}